// Round 2
// baseline (173.297 us; speedup 1.0000x reference)
//
#include <hip/hip_runtime.h>
#include <math.h>

#define KTR 96
#define DIM 256
#define PB  40
#define CH  8
#define MDIM 3840
#define KK  512          // [hi | lo*4096] for XT (test/M);  [lo*4096 | hi] for XE (enroll/N)
#define BM 160           // M-tile (test rows: l,j) = 4 phoneme groups
#define BN 64            // N-tile (enroll cols: k,i) -- halved: 1440 blocks, 4 indep blocks/CU
#define BK 32
#define LDA 40           // f16 elems per LDS row (32 + 8 pad)
#define NTAB 2113        // table nodes, h = 2^-10, x = (i-1056)/1024
#define TPAD 2120

typedef _Float16 v8h __attribute__((ext_vector_type(8)));
typedef float    v4f __attribute__((ext_vector_type(4)));

__device__ __forceinline__ float gate_ref(float x, const float* w, const float* b, const float* v) {
    float g = 0.f;
    #pragma unroll
    for (int c = 0; c < CH; ++c) g = fmaf(v[c], tanhf(fmaf(w[c], x, b[c])), g);
    return g;
}

// ---------------- Kernel 1: L2-normalize + f16 hi/lo split + (extra blocks) gate table ----------------
__global__ __launch_bounds__(256) void k_norm(const float* __restrict__ enroll,
                                              const float* __restrict__ test,
                                              const float* __restrict__ fc1_w,
                                              const float* __restrict__ fc1_b,
                                              const float* __restrict__ fc2_w,
                                              _Float16* __restrict__ XT,
                                              _Float16* __restrict__ XE,
                                              float2* __restrict__ gtabG) {
    int b = blockIdx.x, tid = threadIdx.x;

    if (b >= 2 * KTR) {                       // 9 table-builder blocks
        int i = (b - 2 * KTR) * 256 + tid;
        if (i < NTAB) {
            float w[CH], bb[CH], vv[CH];
            #pragma unroll
            for (int c = 0; c < CH; ++c) { w[c] = fc1_w[c]; bb[c] = fc1_b[c]; vv[c] = fc2_w[c]; }
            float g0 = gate_ref((float)(i - 1056) * 0.0009765625f, w, bb, vv);
            float g1 = gate_ref((float)(i - 1055) * 0.0009765625f, w, bb, vv);
            gtabG[i] = make_float2(g0, g1 - g0);
        }
        return;
    }

    bool isE = (b < KTR);
    int k = isE ? b : b - KTR;
    const float* src = (isE ? enroll : test) + (size_t)k * DIM * PB;

    __shared__ float S[DIM * 41];             // stride 41: conflict-free column walk
    __shared__ float part[6 * PB];
    __shared__ float rn[PB];

    // coalesced float4 stage
    for (int i = tid; i < DIM * PB / 4; i += 256) {
        float4 v = ((const float4*)src)[i];
        int d = i / 10, c = i - d * 10;
        float* p = &S[d * 41 + c * 4];
        p[0] = v.x; p[1] = v.y; p[2] = v.z; p[3] = v.w;
    }
    __syncthreads();
    if (tid < 240) {
        int g = tid / PB, p = tid - (tid / PB) * PB;
        float acc = 0.f;
        for (int d = g; d < DIM; d += 6) {
            float x = S[d * 41 + p];
            acc = fmaf(x, x, acc);
        }
        part[g * PB + p] = acc;
    }
    __syncthreads();
    if (tid < PB) {
        float s = 0.f;
        #pragma unroll
        for (int g = 0; g < 6; ++g) s += part[g * PB + tid];
        rn[tid] = 1.0f / fmaxf(sqrtf(s), 1e-12f);
    }
    __syncthreads();

    // tid == d; stores coalesced 2B along d
    int d = tid;
    for (int p = 0; p < PB; ++p) {
        float v = S[d * 41 + p] * rn[p];
        _Float16 h  = (_Float16)v;
        _Float16 lo = (_Float16)((v - (float)h) * 4096.0f);
        size_t m = (size_t)(k * PB + p);
        if (isE) { XE[m * KK + d] = lo; XE[m * KK + 256 + d] = h;  }
        else     { XT[m * KK + d] = h;  XT[m * KK + 256 + d] = lo; }
    }
}

// ---------------- Kernel 2: reg-staged split-f16 MFMA GEMM + float2 table gate + j-reduction ----------------
// BM=160 x BN=64, 4 waves (2M x 2N), 5x2 fragments/wave. Grid 1440 blocks -> 4 independent
// blocks/CU resident (LDS 34.9KB, VGPR ~75 <= 128 cap) = 16 waves/CU from uncorrelated barriers.
__global__ __launch_bounds__(256, 4) void k_gemm(const _Float16* __restrict__ XT,
                                                 const _Float16* __restrict__ XE,
                                                 const float2* __restrict__ gtabG,
                                                 float* __restrict__ pho2) {
    __shared__ __align__(16) _Float16 LA[BM * LDA];   // 12800 B  (test rows)
    __shared__ __align__(16) _Float16 LB[BN * LDA];   //  5120 B  (enroll rows)
    __shared__ float2 gtab[TPAD];                     // 16960 B  merged val/slope: 1 gather not 2
    // total 34880 B -> 4 blocks/CU

    int tid  = threadIdx.x;
    int lane = tid & 63;
    int wv   = tid >> 6;

    for (int i = tid; i < NTAB; i += 256) gtab[i] = gtabG[i];

    int m0 = blockIdx.y * BM;
    int n0 = blockIdx.x * BN;
    int wm = (wv & 1) * 80;
    int wn = (wv >> 1) * 32;
    int r15 = lane & 15;
    int q4  = lane >> 4;

    v4f acc[5][2];
    #pragma unroll
    for (int mt = 0; mt < 5; ++mt)
        #pragma unroll
        for (int nt = 0; nt < 2; ++nt)
            acc[mt][nt] = (v4f)0.f;

    int aoff[5], boff[2];
    #pragma unroll
    for (int mt = 0; mt < 5; ++mt) aoff[mt] = (wm + mt * 16 + r15) * LDA + q4 * 8;
    #pragma unroll
    for (int nt = 0; nt < 2; ++nt) boff[nt] = (wn + nt * 16 + r15) * LDA + q4 * 8;

    int arow = tid >> 2, aqc = tid & 3;               // 64 rows x 4 chunks
    const uint4* gT = (const uint4*)(XT + (size_t)(m0 + arow) * KK);  // 64 uint4 per row
    const uint4* gE = (const uint4*)(XE + (size_t)(n0 + arow) * KK);
    uint4* lA = (uint4*)LA + (arow * 5 + aqc);
    uint4* lB = (uint4*)LB + (arow * 5 + aqc);

    uint4 va0, va1, va2, vb0;
    #define LOADS(IT) {                                                     \
        int ka = ((IT) < 16) ? (IT) * BK : ((IT) - 16) * BK;                \
        int kb = ((IT) < 16) ? (IT) * BK : 256 + ((IT) - 16) * BK;          \
        int ia = (ka >> 3) + aqc, ib = (kb >> 3) + aqc;                     \
        va0 = gT[ia]; va1 = gT[ia + 64 * 64];                               \
        if (tid < 128) va2 = gT[ia + 128 * 64];                             \
        vb0 = gE[ib]; }

    LOADS(0);
    for (int it = 0; it < 24; ++it) {
        __syncthreads();                               // prev iter's frag reads done
        lA[0]   = va0;
        lA[320] = va1;                                 // +64 rows * 5 chunks
        if (tid < 128) lA[640] = va2;                  // rows 128..159
        lB[0]   = vb0;                                 // rows 0..63 only (BN=64)
        __syncthreads();

        if (it < 23) LOADS(it + 1);                    // prefetch overlaps MFMA below

        if (it == 16) {                                // cross terms done: scale by 2^-12 (exact)
            #pragma unroll
            for (int mt = 0; mt < 5; ++mt)
                #pragma unroll
                for (int nt = 0; nt < 2; ++nt)
                    acc[mt][nt] *= 0.000244140625f;
        }

        v8h af[5], bf[2];
        #pragma unroll
        for (int mt = 0; mt < 5; ++mt) af[mt] = *(const v8h*)(LA + aoff[mt]);
        #pragma unroll
        for (int nt = 0; nt < 2; ++nt) bf[nt] = *(const v8h*)(LB + boff[nt]);
        #pragma unroll
        for (int mt = 0; mt < 5; ++mt)
            #pragma unroll
            for (int nt = 0; nt < 2; ++nt)
                acc[mt][nt] = __builtin_amdgcn_mfma_f32_16x16x32_f16(af[mt], bf[nt], acc[mt][nt], 0, 0, 0);
    }
    #undef LOADS

    // ---- epilogue: D row = q4*4+r (test: l,j), col = r15 (enroll: k,i) ----
    const float inv40 = 1.0f / (40.0f + 1e-6f);
    int lg = (m0 + wm) / PB;                           // wave covers groups lg, lg+1
    #pragma unroll
    for (int nt = 0; nt < 2; ++nt) {
        float s0 = 0.f, s1 = 0.f, t2 = 0.f;
        #pragma unroll
        for (int mt = 0; mt < 5; ++mt) {
            #pragma unroll
            for (int r = 0; r < 4; ++r) {
                float x = acc[mt][nt][r];
                float u = fmaf(x, 1024.0f, 1056.0f);
                int i = (int)u;
                i = min(max(i, 0), NTAB - 2);
                float f = u - (float)i;
                float2 t = gtab[i];                    // single b64 gather
                float g = fmaf(f, t.y, t.x);
                float xg = g * x;
                if (mt < 2)       s0 += xg;            // rows 0..31  -> group lg
                else if (mt == 2) t2 += xg;            // rows 32..47 -> straddle
                else              s1 += xg;            // rows 48..79 -> group lg+1
            }
        }
        bool lo = (q4 < 2);                            // mt=2: q4<2 -> rows 32..39 (lg)
        s0 += lo ? t2 : 0.f;
        s1 += lo ? 0.f : t2;
        s0 += __shfl_xor(s0, 16); s0 += __shfl_xor(s0, 32);
        s1 += __shfl_xor(s1, 16); s1 += __shfl_xor(s1, 32);
        if (q4 == 0) {
            int n = n0 + wn + nt * 16 + r15;
            int kk = n / PB, ii = n - kk * PB;
            pho2[((size_t)kk * KTR + lg)     * PB + ii] = s0 * inv40;
            pho2[((size_t)kk * KTR + lg + 1) * PB + ii] = s1 * inv40;
        }
    }
}

// ---------------- Kernel 3: gate (full range -> tanhf) + i-reduction -> [K,K] ----------------
__global__ __launch_bounds__(256) void k_final(const float* __restrict__ pho2,
                                               const float* __restrict__ fc1_w,
                                               const float* __restrict__ fc1_b,
                                               const float* __restrict__ fc2_w,
                                               float* __restrict__ out) {
    int wv = threadIdx.x >> 6;
    int lane = threadIdx.x & 63;
    int pair = blockIdx.x * 4 + wv;

    float w[CH], bb[CH], vv[CH];
    #pragma unroll
    for (int c = 0; c < CH; ++c) { w[c] = fc1_w[c]; bb[c] = fc1_b[c]; vv[c] = fc2_w[c]; }

    float x = (lane < PB) ? pho2[(size_t)pair * PB + lane] : 0.f;
    float s = gate_ref(x, w, bb, vv) * x;

    #pragma unroll
    for (int off = 32; off; off >>= 1) s += __shfl_xor(s, off);
    if (lane == 0) out[pair] = s / (40.0f + 1e-6f);
}

extern "C" void kernel_launch(void* const* d_in, const int* in_sizes, int n_in,
                              void* d_out, int out_size, void* d_ws, size_t ws_size,
                              hipStream_t stream) {
    const float* enroll = (const float*)d_in[0];
    const float* test   = (const float*)d_in[1];
    const float* fc1_w  = (const float*)d_in[2];
    const float* fc1_b  = (const float*)d_in[3];
    const float* fc2_w  = (const float*)d_in[4];
    float* out = (float*)d_out;

    _Float16* XT = (_Float16*)d_ws;                    // [3840][512] f16 (test:  hi|lo')
    _Float16* XE = XT + (size_t)MDIM * KK;             // [3840][512] f16 (enroll: lo'|hi)
    float* pho2  = (float*)(XE + (size_t)MDIM * KK);   // [96*96*40] f32
    float2* gtabG = (float2*)(pho2 + (size_t)KTR * KTR * PB);

    k_norm<<<2 * KTR + 9, 256, 0, stream>>>(enroll, test, fc1_w, fc1_b, fc2_w, XT, XE, gtabG);
    dim3 g2(MDIM / BN, MDIM / BM);                     // (60, 24)
    k_gemm<<<g2, 256, 0, stream>>>(XT, XE, gtabG, pho2);
    k_final<<<KTR * KTR / 4, 256, 0, stream>>>(pho2, fc1_w, fc1_b, fc2_w, out);
}

// Round 3
// 116.959 us; speedup vs baseline: 1.4817x; 1.4817x over previous
//
#include <hip/hip_runtime.h>
#include <math.h>

#define KTR 96
#define DIM 256
#define PB  40
#define CH  8
#define MDIM 3840
#define KK  512          // [hi | lo*4096] for XT (test/M);  [lo*4096 | hi] for XE (enroll/N)
#define BM 160           // M-tile (test rows: l,j) = 4 phoneme groups
#define BN 64            // N-tile (enroll cols: k,i): 1440 blocks -> 4 indep blocks/CU
#define BK 32
#define LDA 40           // f16 elems per LDS row (32 + 8 pad)
#define NTAB 2113        // table nodes, h = 2^-10, x = (i-1056)/1024
#define TPAD 2120

typedef _Float16 v8h __attribute__((ext_vector_type(8)));
typedef float    v4f __attribute__((ext_vector_type(4)));

__device__ __forceinline__ float gate_ref(float x, const float* w, const float* b, const float* v) {
    float g = 0.f;
    #pragma unroll
    for (int c = 0; c < CH; ++c) g = fmaf(v[c], tanhf(fmaf(w[c], x, b[c])), g);
    return g;
}

// ---------------- Kernel 1: L2-normalize + f16 hi/lo split + (extra blocks) gate table ----------------
__global__ __launch_bounds__(256) void k_norm(const float* __restrict__ enroll,
                                              const float* __restrict__ test,
                                              const float* __restrict__ fc1_w,
                                              const float* __restrict__ fc1_b,
                                              const float* __restrict__ fc2_w,
                                              _Float16* __restrict__ XT,
                                              _Float16* __restrict__ XE,
                                              float2* __restrict__ gtabG) {
    int b = blockIdx.x, tid = threadIdx.x;

    if (b >= 2 * KTR) {                       // 9 table-builder blocks
        int i = (b - 2 * KTR) * 256 + tid;
        if (i < NTAB) {
            float w[CH], bb[CH], vv[CH];
            #pragma unroll
            for (int c = 0; c < CH; ++c) { w[c] = fc1_w[c]; bb[c] = fc1_b[c]; vv[c] = fc2_w[c]; }
            float g0 = gate_ref((float)(i - 1056) * 0.0009765625f, w, bb, vv);
            float g1 = gate_ref((float)(i - 1055) * 0.0009765625f, w, bb, vv);
            gtabG[i] = make_float2(g0, g1 - g0);
        }
        return;
    }

    bool isE = (b < KTR);
    int k = isE ? b : b - KTR;
    const float* src = (isE ? enroll : test) + (size_t)k * DIM * PB;

    __shared__ float S[DIM * 41];             // stride 41: conflict-free column walk
    __shared__ float part[6 * PB];
    __shared__ float rn[PB];

    // coalesced float4 stage
    for (int i = tid; i < DIM * PB / 4; i += 256) {
        float4 v = ((const float4*)src)[i];
        int d = i / 10, c = i - d * 10;
        float* p = &S[d * 41 + c * 4];
        p[0] = v.x; p[1] = v.y; p[2] = v.z; p[3] = v.w;
    }
    __syncthreads();
    if (tid < 240) {
        int g = tid / PB, p = tid - (tid / PB) * PB;
        float acc = 0.f;
        for (int d = g; d < DIM; d += 6) {
            float x = S[d * 41 + p];
            acc = fmaf(x, x, acc);
        }
        part[g * PB + p] = acc;
    }
    __syncthreads();
    if (tid < PB) {
        float s = 0.f;
        #pragma unroll
        for (int g = 0; g < 6; ++g) s += part[g * PB + tid];
        rn[tid] = 1.0f / fmaxf(sqrtf(s), 1e-12f);
    }
    __syncthreads();

    // tid == d; stores coalesced 2B along d
    int d = tid;
    for (int p = 0; p < PB; ++p) {
        float v = S[d * 41 + p] * rn[p];
        _Float16 h  = (_Float16)v;
        _Float16 lo = (_Float16)((v - (float)h) * 4096.0f);
        size_t m = (size_t)(k * PB + p);
        if (isE) { XE[m * KK + d] = lo; XE[m * KK + 256 + d] = h;  }
        else     { XT[m * KK + d] = h;  XT[m * KK + 256 + d] = lo; }
    }
}

// ---------------- Kernel 2: reg-staged split-f16 MFMA GEMM + float2 table gate + j-reduction ----------------
// BM=160 x BN=64, 4 waves (2M x 2N), 5x2 fragments/wave.
// __launch_bounds__(256,2): 256-reg cap -- round-2's (256,4)=128 cap spilled the loop-carried
// staging regs to scratch (WRITE_SIZE 78MB vs pho2's 1.4MB). Occupancy comes from LDS (34.9KB
// -> 4 blocks/CU), not from the bound.
// XCD swizzle: 1440 blocks % 8 == 0 -> bijective chunked remap; each XCD owns 180 consecutive
// tiles = 3 whole M-panels -> A panels + XE (~4.4MB) L2-resident per XCD.
__global__ __launch_bounds__(256, 2) void k_gemm(const _Float16* __restrict__ XT,
                                                 const _Float16* __restrict__ XE,
                                                 const float2* __restrict__ gtabG,
                                                 float* __restrict__ pho2) {
    __shared__ __align__(16) _Float16 LA[BM * LDA];   // 12800 B  (test rows)
    __shared__ __align__(16) _Float16 LB[BN * LDA];   //  5120 B  (enroll rows)
    __shared__ float2 gtab[TPAD];                     // 16960 B  merged val/slope: 1 gather not 2
    // total 34880 B -> 4 blocks/CU

    int tid  = threadIdx.x;
    int lane = tid & 63;
    int wv   = tid >> 6;

    for (int i = tid; i < NTAB; i += 256) gtab[i] = gtabG[i];

    int id = blockIdx.y * 60 + blockIdx.x;            // launch index; default XCD = id & 7
    int wg = (id & 7) * 180 + (id >> 3);              // bijective: 180 consecutive tiles per XCD
    int m0 = (wg / 60) * BM;
    int n0 = (wg % 60) * BN;
    int wm = (wv & 1) * 80;
    int wn = (wv >> 1) * 32;
    int r15 = lane & 15;
    int q4  = lane >> 4;

    v4f acc[5][2];
    #pragma unroll
    for (int mt = 0; mt < 5; ++mt)
        #pragma unroll
        for (int nt = 0; nt < 2; ++nt)
            acc[mt][nt] = (v4f)0.f;

    int aoff[5], boff[2];
    #pragma unroll
    for (int mt = 0; mt < 5; ++mt) aoff[mt] = (wm + mt * 16 + r15) * LDA + q4 * 8;
    #pragma unroll
    for (int nt = 0; nt < 2; ++nt) boff[nt] = (wn + nt * 16 + r15) * LDA + q4 * 8;

    int arow = tid >> 2, aqc = tid & 3;               // 64 rows x 4 chunks
    const uint4* gT = (const uint4*)(XT + (size_t)(m0 + arow) * KK);  // 64 uint4 per row
    const uint4* gE = (const uint4*)(XE + (size_t)(n0 + arow) * KK);
    uint4* lA = (uint4*)LA + (arow * 5 + aqc);
    uint4* lB = (uint4*)LB + (arow * 5 + aqc);

    uint4 va0, va1, va2, vb0;
    #define LOADS(IT) {                                                     \
        int ka = ((IT) < 16) ? (IT) * BK : ((IT) - 16) * BK;                \
        int kb = ((IT) < 16) ? (IT) * BK : 256 + ((IT) - 16) * BK;          \
        int ia = (ka >> 3) + aqc, ib = (kb >> 3) + aqc;                     \
        va0 = gT[ia]; va1 = gT[ia + 64 * 64];                               \
        if (tid < 128) va2 = gT[ia + 128 * 64];                             \
        vb0 = gE[ib]; }

    LOADS(0);
    for (int it = 0; it < 24; ++it) {
        __syncthreads();                               // prev iter's frag reads done
        lA[0]   = va0;
        lA[320] = va1;                                 // +64 rows * 5 chunks
        if (tid < 128) lA[640] = va2;                  // rows 128..159
        lB[0]   = vb0;                                 // rows 0..63 only (BN=64)
        __syncthreads();

        if (it < 23) LOADS(it + 1);                    // prefetch overlaps MFMA below

        if (it == 16) {                                // cross terms done: scale by 2^-12 (exact)
            #pragma unroll
            for (int mt = 0; mt < 5; ++mt)
                #pragma unroll
                for (int nt = 0; nt < 2; ++nt)
                    acc[mt][nt] *= 0.000244140625f;
        }

        v8h af[5], bf[2];
        #pragma unroll
        for (int mt = 0; mt < 5; ++mt) af[mt] = *(const v8h*)(LA + aoff[mt]);
        #pragma unroll
        for (int nt = 0; nt < 2; ++nt) bf[nt] = *(const v8h*)(LB + boff[nt]);
        #pragma unroll
        for (int mt = 0; mt < 5; ++mt)
            #pragma unroll
            for (int nt = 0; nt < 2; ++nt)
                acc[mt][nt] = __builtin_amdgcn_mfma_f32_16x16x32_f16(af[mt], bf[nt], acc[mt][nt], 0, 0, 0);
    }
    #undef LOADS

    // ---- epilogue: D row = q4*4+r (test: l,j), col = r15 (enroll: k,i) ----
    const float inv40 = 1.0f / (40.0f + 1e-6f);
    int lg = (m0 + wm) / PB;                           // wave covers groups lg, lg+1
    #pragma unroll
    for (int nt = 0; nt < 2; ++nt) {
        float s0 = 0.f, s1 = 0.f, t2 = 0.f;
        #pragma unroll
        for (int mt = 0; mt < 5; ++mt) {
            #pragma unroll
            for (int r = 0; r < 4; ++r) {
                float x = acc[mt][nt][r];
                float u = fmaf(x, 1024.0f, 1056.0f);
                int i = (int)u;
                i = min(max(i, 0), NTAB - 2);
                float f = u - (float)i;
                float2 t = gtab[i];                    // single b64 gather
                float g = fmaf(f, t.y, t.x);
                float xg = g * x;
                if (mt < 2)       s0 += xg;            // rows 0..31  -> group lg
                else if (mt == 2) t2 += xg;            // rows 32..47 -> straddle
                else              s1 += xg;            // rows 48..79 -> group lg+1
            }
        }
        bool lo = (q4 < 2);                            // mt=2: q4<2 -> rows 32..39 (lg)
        s0 += lo ? t2 : 0.f;
        s1 += lo ? 0.f : t2;
        s0 += __shfl_xor(s0, 16); s0 += __shfl_xor(s0, 32);
        s1 += __shfl_xor(s1, 16); s1 += __shfl_xor(s1, 32);
        if (q4 == 0) {
            int n = n0 + wn + nt * 16 + r15;
            int kk = n / PB, ii = n - kk * PB;
            pho2[((size_t)kk * KTR + lg)     * PB + ii] = s0 * inv40;
            pho2[((size_t)kk * KTR + lg + 1) * PB + ii] = s1 * inv40;
        }
    }
}

// ---------------- Kernel 3: gate (full range -> tanhf) + i-reduction -> [K,K] ----------------
__global__ __launch_bounds__(256) void k_final(const float* __restrict__ pho2,
                                               const float* __restrict__ fc1_w,
                                               const float* __restrict__ fc1_b,
                                               const float* __restrict__ fc2_w,
                                               float* __restrict__ out) {
    int wv = threadIdx.x >> 6;
    int lane = threadIdx.x & 63;
    int pair = blockIdx.x * 4 + wv;

    float w[CH], bb[CH], vv[CH];
    #pragma unroll
    for (int c = 0; c < CH; ++c) { w[c] = fc1_w[c]; bb[c] = fc1_b[c]; vv[c] = fc2_w[c]; }

    float x = (lane < PB) ? pho2[(size_t)pair * PB + lane] : 0.f;
    float s = gate_ref(x, w, bb, vv) * x;

    #pragma unroll
    for (int off = 32; off; off >>= 1) s += __shfl_xor(s, off);
    if (lane == 0) out[pair] = s / (40.0f + 1e-6f);
}

extern "C" void kernel_launch(void* const* d_in, const int* in_sizes, int n_in,
                              void* d_out, int out_size, void* d_ws, size_t ws_size,
                              hipStream_t stream) {
    const float* enroll = (const float*)d_in[0];
    const float* test   = (const float*)d_in[1];
    const float* fc1_w  = (const float*)d_in[2];
    const float* fc1_b  = (const float*)d_in[3];
    const float* fc2_w  = (const float*)d_in[4];
    float* out = (float*)d_out;

    _Float16* XT = (_Float16*)d_ws;                    // [3840][512] f16 (test:  hi|lo')
    _Float16* XE = XT + (size_t)MDIM * KK;             // [3840][512] f16 (enroll: lo'|hi)
    float* pho2  = (float*)(XE + (size_t)MDIM * KK);   // [96*96*40] f32
    float2* gtabG = (float2*)(pho2 + (size_t)KTR * KTR * PB);

    k_norm<<<2 * KTR + 9, 256, 0, stream>>>(enroll, test, fc1_w, fc1_b, fc2_w, XT, XE, gtabG);
    dim3 g2(MDIM / BN, MDIM / BM);                     // (60, 24)
    k_gemm<<<g2, 256, 0, stream>>>(XT, XE, gtabG, pho2);
    k_final<<<KTR * KTR / 4, 256, 0, stream>>>(pho2, fc1_w, fc1_b, fc2_w, out);
}